// Round 12
// baseline (58.085 us; speedup 1.0000x reference)
//
#include <hip/hip_runtime.h>

// Problem sizes (fixed by the reference)
#define BDIM 8
#define QDIM 1024
#define KDIM 1024
#define HDIM 64   // = DQ = DK = DV
#define KTPC 2    // k-tiles (64 keys) per chunk -> uniform block cost
#define MAXCH 8   // ceil(16/KTPC)

constexpr float kLog2e = 1.4426950408889634f;
constexpr float kC2 = 2.0f * kLog2e;

// ---------------------------------------------------------------------------
// K1: both projections; emits Eq/Ek = min(exp2(kC2 * (X@W)), 2^15).
// ---------------------------------------------------------------------------
__global__ __launch_bounds__(256) void proj_both(
    const float* __restrict__ queries, const float* __restrict__ keys,
    const float* __restrict__ Wq, const float* __restrict__ Wk,
    float* __restrict__ eq, float* __restrict__ ek) {
  const int bid = blockIdx.x;
  const bool isK = bid >= 256;
  const float* X = isK ? keys : queries;
  const float* W = isK ? Wk : Wq;
  float* Y = isK ? ek : eq;
  const long long base = (long long)(bid & 255) * 32 * 64;

  __shared__ __align__(16) float xs[32][68];
  __shared__ __align__(16) float ws[64][64];
  const int t = threadIdx.x;
  {
    const int r = t >> 4, sl = t & 15;
#pragma unroll
    for (int i = 0; i < 2; ++i)
      *(float4*)&xs[r + i * 16][sl * 4] =
          *(const float4*)&X[base + (long long)(r + i * 16) * 64 + sl * 4];
#pragma unroll
    for (int i = 0; i < 4; ++i)
      *(float4*)&ws[r + i * 16][sl * 4] =
          *(const float4*)&W[(r + i * 16) * 64 + sl * 4];
  }
  __syncthreads();

  const int r = t >> 3;            // 0..31
  const int c0 = (t & 7) * 8;      // 8 output cols per thread
  float acc[8];
#pragma unroll
  for (int j = 0; j < 8; ++j) acc[j] = 0.0f;

#pragma unroll 8
  for (int d = 0; d < 64; ++d) {
    const float xv = xs[r][d];
#pragma unroll
    for (int j4 = 0; j4 < 2; ++j4) {
      float4 w4 = *(float4*)&ws[d][c0 + j4 * 4];
      acc[j4 * 4 + 0] = fmaf(xv, w4.x, acc[j4 * 4 + 0]);
      acc[j4 * 4 + 1] = fmaf(xv, w4.y, acc[j4 * 4 + 1]);
      acc[j4 * 4 + 2] = fmaf(xv, w4.z, acc[j4 * 4 + 2]);
      acc[j4 * 4 + 3] = fmaf(xv, w4.w, acc[j4 * 4 + 3]);
    }
  }
#pragma unroll
  for (int j4 = 0; j4 < 2; ++j4) {
    float4 o = make_float4(
        fminf(__builtin_amdgcn_exp2f(acc[j4 * 4 + 0] * kC2), 32768.0f),
        fminf(__builtin_amdgcn_exp2f(acc[j4 * 4 + 1] * kC2), 32768.0f),
        fminf(__builtin_amdgcn_exp2f(acc[j4 * 4 + 2] * kC2), 32768.0f),
        fminf(__builtin_amdgcn_exp2f(acc[j4 * 4 + 3] * kC2), 32768.0f));
    *(float4*)&Y[base + (long long)r * 64 + c0 + j4 * 4] = o;
  }
}

// ---------------------------------------------------------------------------
// K2: fused scores + softmax-numerator + PV over one chunk (<=2 k-tiles).
// 2q x 4k per thread: block = 32 q-rows x 256 thr, thread (tq2=t>>4, kg=t&15)
// owns rows {tq2, tq2+16} x 4 k. Per stage 6 LDS reads feed 8 QUADs (was
// 5 reads / 4 QUADs); PV vs-reads shared across the 2 rows. No online max
// (|score| <= sum|wv| uniform bound). ps produce/consume wave-internal.
// LDS 48.5 KB -> 3 blocks/CU (12 waves/CU).
// ---------------------------------------------------------------------------
__global__ __launch_bounds__(256, 3) void fused_kernel(
    const float* __restrict__ eqp, const float* __restrict__ ekp,
    const float* __restrict__ vglob, const float* __restrict__ wv,
    const int* __restrict__ vlens, float* __restrict__ part_o,
    float* __restrict__ part_l) {
  // ---- uniform worklist mapping (scalar) ----
  int pre[9];
  pre[0] = 0;
#pragma unroll
  for (int bb = 0; bb < 8; ++bb) {
    int nt = (vlens[bb] + 63) >> 6;
    nt = nt < 16 ? nt : 16;
    const int nch = (nt + KTPC - 1) / KTPC;
    pre[bb + 1] = pre[bb] + (nch << 5);  // nch chunks x 32 q-tiles (32 rows)
  }
  const int g = blockIdx.x;
  if (g >= pre[8]) return;
  int b = 0;
#pragma unroll
  for (int i = 0; i < 7; ++i) b += (g >= pre[i + 1]);
  const int local = g - pre[b];
  const int qt = local & 31;   // q-tile fastest (adjacent blocks share chunk)
  const int ch = local >> 5;
  const int q0 = qt * 32;
  const int vlen = vlens[b];
  int nt = (vlen + 63) >> 6;
  nt = nt < 16 ? nt : 16;
  const int kt0 = ch * KTPC;
  const int ktend = (kt0 + KTPC < nt) ? kt0 + KTPC : nt;

  __shared__ __align__(16) float qs[32][68];  // 8.5 KB (+4 pad: row-pair 2-way)
  __shared__ __align__(16) float ks[64][64];  // 16 KB XOR-swizzled Ek
  __shared__ __align__(16) float vs[64][64];  // 16 KB V (linear)
  __shared__ __align__(16) float ps[32][64];  // 8 KB, column-rotated by row
  const int t = threadIdx.x;
  const int tq2 = t >> 4;          // 0..15 -> rows tq2 and tq2+16
  const int r0 = tq2, r1 = tq2 + 16;
  const int kg = t & 15;           // k group / d group
  const int kbs = kg << 2;
  const int key0 = ((kbs + 0) ^ kg) & 15;
  const int key1 = ((kbs + 1) ^ kg) & 15;
  const int key2 = ((kbs + 2) ^ kg) & 15;
  const int key3 = ((kbs + 3) ^ kg) & 15;
  const int pcol = (kg + r0) & 15;  // rotated ps column ((kg+r1)&15 == pcol)

  float sumw = 0.0f, sumabs = 0.0f;
#pragma unroll
  for (int h = 0; h < 64; ++h) {   // uniform -> scalar loads
    const float w = wv[h];
    sumw += w;
    sumabs += fabsf(w);
  }
  const float sbias = sumw - sumabs;  // s' = -2*acc + sbias <= 0 always

  {  // Q rows: 32x64 floats = 512 float4, two per thread
#pragma unroll
    for (int i = 0; i < 2; ++i) {
      const int f = i * 256 + t;
      const int r = f >> 4, sl = f & 15;
      *(float4*)&qs[r][sl * 4] =
          *(const float4*)&eqp[(long long)(b * QDIM + q0 + r) * 64 + sl * 4];
    }
  }

  float4 oA = make_float4(0.0f, 0.0f, 0.0f, 0.0f);
  float4 oB = make_float4(0.0f, 0.0f, 0.0f, 0.0f);
  float lA = 0.0f, lB = 0.0f;

  for (int kt = kt0; kt < ktend; ++kt) {
    __syncthreads();  // prev PV done reading vs/ps
    // stage Ek (swizzled) + V (linear): 4 float4 each per thread
#pragma unroll
    for (int i = 0; i < 4; ++i) {
      const int f = i * 256 + t;
      const int k = f >> 4, sl = f & 15;
      const int key = (k ^ (k >> 2)) & 15;
      const long long grow = (long long)(b * KDIM + kt * 64 + k) * 64 + sl * 4;
      *(float4*)&ks[k][(sl ^ key) * 4] = *(const float4*)&ekp[grow];
      *(float4*)&vs[k][sl * 4] = *(const float4*)&vglob[grow];
    }
    __syncthreads();

    // ---- scores: 2 rows x 4 k, reg double-buffered h-pipeline ----
    float accA0 = 0.0f, accA1 = 0.0f, accA2 = 0.0f, accA3 = 0.0f;
    float accB0 = 0.0f, accB1 = 0.0f, accB2 = 0.0f, accB3 = 0.0f;
    float4 qA0, qB0, kA0, kA1, kA2, kA3;
    float4 qA1, qB1, kB0, kB1, kB2, kB3;

#define LOAD_STAGE(QA, QB, K0, K1, K2, K3, H)              \
  QA = *(const float4*)&qs[r0][(H) * 4];                   \
  QB = *(const float4*)&qs[r1][(H) * 4];                   \
  K0 = *(const float4*)&ks[kbs + 0][((H) ^ key0) * 4];     \
  K1 = *(const float4*)&ks[kbs + 1][((H) ^ key1) * 4];     \
  K2 = *(const float4*)&ks[kbs + 2][((H) ^ key2) * 4];     \
  K3 = *(const float4*)&ks[kbs + 3][((H) ^ key3) * 4];

// quad rational: acc += (n01*d23 + n23*d01) * rcp(d01*d23), ui = 1+Eq*Ek
#define QUAD(ACC, QF, KF, W0, W1, W2, W3)                  \
  {                                                        \
    const float u0 = fmaf(QF.x, KF.x, 1.0f);               \
    const float u1 = fmaf(QF.y, KF.y, 1.0f);               \
    const float u2 = fmaf(QF.z, KF.z, 1.0f);               \
    const float u3 = fmaf(QF.w, KF.w, 1.0f);               \
    const float d01 = u0 * u1;                             \
    const float d23 = u2 * u3;                             \
    const float n01 = fmaf(W1, u0, W0 * u1);               \
    const float n23 = fmaf(W3, u2, W2 * u3);               \
    const float num = fmaf(n23, d01, n01 * d23);           \
    ACC = fmaf(num, __builtin_amdgcn_rcpf(d01 * d23), ACC);\
  }

#define COMP_STAGE(QA, QB, K0, K1, K2, K3, H)              \
  {                                                        \
    const float w0 = wv[(H) * 4 + 0];                      \
    const float w1 = wv[(H) * 4 + 1];                      \
    const float w2 = wv[(H) * 4 + 2];                      \
    const float w3 = wv[(H) * 4 + 3];                      \
    QUAD(accA0, QA, K0, w0, w1, w2, w3)                    \
    QUAD(accA1, QA, K1, w0, w1, w2, w3)                    \
    QUAD(accA2, QA, K2, w0, w1, w2, w3)                    \
    QUAD(accA3, QA, K3, w0, w1, w2, w3)                    \
    QUAD(accB0, QB, K0, w0, w1, w2, w3)                    \
    QUAD(accB1, QB, K1, w0, w1, w2, w3)                    \
    QUAD(accB2, QB, K2, w0, w1, w2, w3)                    \
    QUAD(accB3, QB, K3, w0, w1, w2, w3)                    \
  }

    LOAD_STAGE(qA0, qA1, kA0, kA1, kA2, kA3, 0)
#pragma unroll
    for (int h = 0; h < 16; h += 2) {
      LOAD_STAGE(qB0, qB1, kB0, kB1, kB2, kB3, h + 1)
      COMP_STAGE(qA0, qA1, kA0, kA1, kA2, kA3, h)
      if (h + 2 < 16) LOAD_STAGE(qA0, qA1, kA0, kA1, kA2, kA3, h + 2)
      COMP_STAGE(qB0, qB1, kB0, kB1, kB2, kB3, h + 1)
    }
#undef LOAD_STAGE
#undef COMP_STAGE
#undef QUAD

    // ---- p = exp2(s - sumabs); masked lanes -> exact 0; no reductions ----
    const int kgl = kt * 64 + kbs;
    const bool v0 = kgl + 0 < vlen, v1 = kgl + 1 < vlen;
    const bool v2 = kgl + 2 < vlen, v3 = kgl + 3 < vlen;
    float sA0 = v0 ? fmaf(-2.0f, accA0, sbias) : -3.0e38f;
    float sA1 = v1 ? fmaf(-2.0f, accA1, sbias) : -3.0e38f;
    float sA2 = v2 ? fmaf(-2.0f, accA2, sbias) : -3.0e38f;
    float sA3 = v3 ? fmaf(-2.0f, accA3, sbias) : -3.0e38f;
    float sB0 = v0 ? fmaf(-2.0f, accB0, sbias) : -3.0e38f;
    float sB1 = v1 ? fmaf(-2.0f, accB1, sbias) : -3.0e38f;
    float sB2 = v2 ? fmaf(-2.0f, accB2, sbias) : -3.0e38f;
    float sB3 = v3 ? fmaf(-2.0f, accB3, sbias) : -3.0e38f;
    const float pA0 = __builtin_amdgcn_exp2f(sA0 * kLog2e);
    const float pA1 = __builtin_amdgcn_exp2f(sA1 * kLog2e);
    const float pA2 = __builtin_amdgcn_exp2f(sA2 * kLog2e);
    const float pA3 = __builtin_amdgcn_exp2f(sA3 * kLog2e);
    const float pB0 = __builtin_amdgcn_exp2f(sB0 * kLog2e);
    const float pB1 = __builtin_amdgcn_exp2f(sB1 * kLog2e);
    const float pB2 = __builtin_amdgcn_exp2f(sB2 * kLog2e);
    const float pB3 = __builtin_amdgcn_exp2f(sB3 * kLog2e);
    lA += (pA0 + pA1) + (pA2 + pA3);
    lB += (pB0 + pB1) + (pB2 + pB3);
    // rotated stores (col pcol holds k-group kg for rows r0 and r1)
    *(float4*)&ps[r0][pcol * 4] = make_float4(pA0, pA1, pA2, pA3);
    *(float4*)&ps[r1][pcol * 4] = make_float4(pB0, pB1, pB2, pB3);
    // wave-internal produce/consume: no barrier needed.

    // ---- PV: o += sum_k p[k] * vs[k][kbs..kbs+3], vs reads shared ----
#pragma unroll 4
    for (int k4 = 0; k4 < 16; ++k4) {
      const float4 pa = *(const float4*)&ps[r0][((k4 + r0) & 15) * 4];
      const float4 pb = *(const float4*)&ps[r1][((k4 + r1) & 15) * 4];
      const float pwA[4] = {pa.x, pa.y, pa.z, pa.w};
      const float pwB[4] = {pb.x, pb.y, pb.z, pb.w};
#pragma unroll
      for (int e = 0; e < 4; ++e) {
        const float4 vv = *(const float4*)&vs[k4 * 4 + e][kbs];
        oA.x = fmaf(pwA[e], vv.x, oA.x);
        oA.y = fmaf(pwA[e], vv.y, oA.y);
        oA.z = fmaf(pwA[e], vv.z, oA.z);
        oA.w = fmaf(pwA[e], vv.w, oA.w);
        oB.x = fmaf(pwB[e], vv.x, oB.x);
        oB.y = fmaf(pwB[e], vv.y, oB.y);
        oB.z = fmaf(pwB[e], vv.z, oB.z);
        oB.w = fmaf(pwB[e], vv.w, oB.w);
      }
    }
  }

  // ---- reduce l over the 16 kg lanes (in-wave), write chunk partials ----
#pragma unroll
  for (int s = 1; s < 16; s <<= 1) {
    lA += __shfl_xor(lA, s, 64);
    lB += __shfl_xor(lB, s, 64);
  }
  *(float4*)&part_o[((long long)g * 32 + r0) * 64 + kbs] = oA;
  *(float4*)&part_o[((long long)g * 32 + r1) * 64 + kbs] = oB;
  if (kg == 0) {
    part_l[g * 32 + r0] = lA;
    part_l[g * 32 + r1] = lB;
  }
}

// ---------------------------------------------------------------------------
// K3: combine <=MAXCH chunk partials per q-row: plain sums (common shift
// cancels). 256 thr = 4 rows x 64 lanes.
// ---------------------------------------------------------------------------
__global__ __launch_bounds__(256) void combine_kernel(
    const float* __restrict__ part_o, const float* __restrict__ part_l,
    const int* __restrict__ vlens, float* __restrict__ out) {
  int pre[8], nchv[8];
  int run = 0;
#pragma unroll
  for (int bb = 0; bb < 8; ++bb) {
    int nt = (vlens[bb] + 63) >> 6;
    nt = nt < 16 ? nt : 16;
    nchv[bb] = (nt + KTPC - 1) / KTPC;
    pre[bb] = run;
    run += nchv[bb] << 5;
  }
  const int t = threadIdx.x;
  const int row = blockIdx.x * 4 + (t >> 6);
  const int lane = t & 63;
  const int b = row >> 10;
  const int q = row & (QDIM - 1);
  const int qt = q >> 5;           // 32-row q-tiles
  const int tq = q & 31;
  const int nch = nchv[b];
  const int slot0 = pre[b] + qt;   // slot for chunk c = slot0 + c*32

  float L = 0.0f, acc = 0.0f;
#pragma unroll
  for (int c = 0; c < MAXCH; ++c) {
    if (c < nch) {
      L += part_l[(slot0 + (c << 5)) * 32 + tq];
      acc += part_o[((long long)(slot0 + (c << 5)) * 32 + tq) * 64 + lane];
    }
  }
  out[(long long)row * 64 + lane] = acc * __builtin_amdgcn_rcpf(L);
}

// ---------------------------------------------------------------------------
extern "C" void kernel_launch(void* const* d_in, const int* in_sizes, int n_in,
                              void* d_out, int out_size, void* d_ws, size_t ws_size,
                              hipStream_t stream) {
  const float* queries = (const float*)d_in[0];
  const float* keys    = (const float*)d_in[1];
  const float* values  = (const float*)d_in[2];
  const int*   vlens   = (const int*)d_in[3];
  const float* Wq      = (const float*)d_in[4];
  const float* Wk      = (const float*)d_in[5];
  const float* wv      = (const float*)d_in[6];
  float* out = (float*)d_out;

  float* eq     = (float*)d_ws;                      // B*Q*H = 2 MB
  float* ek     = eq + (size_t)BDIM * QDIM * HDIM;   // B*K*H = 2 MB
  float* part_o = ek + (size_t)BDIM * KDIM * HDIM;   // 2048*32*64*4 = 16.8 MB
  float* part_l = part_o + (size_t)2048 * 32 * 64;   // 256 KB

  proj_both<<<dim3(512), 256, 0, stream>>>(queries, keys, Wq, Wk, eq, ek);
  // max worklist = 8 b * 8 chunks * 32 q-tiles = 2048; invalid tail exits.
  fused_kernel<<<dim3(2048), 256, 0, stream>>>(eq, ek, values, wv, vlens,
                                               part_o, part_l);
  combine_kernel<<<dim3(BDIM * QDIM / 4), 256, 0, stream>>>(part_o, part_l,
                                                            vlens, out);
}